// Round 1
// baseline (922.237 us; speedup 1.0000x reference)
//
#include <hip/hip_runtime.h>

#define DHW (128*128*128)

// Kernel 1: per-batch rotation matrix from im_feat @ pos_w.T + pos_b.
// R = rot_y(mu) @ rot_x(rho) =
//   [ cm,  sm*sr, -sm*cr ]
//   [ 0,   cr,     sr    ]
//   [ sm, -cm*sr,  cm*cr ]
__global__ void compute_R_kernel(const float* __restrict__ im_feat,
                                 const float* __restrict__ pos_w,
                                 const float* __restrict__ pos_b,
                                 float* __restrict__ Rout) {
    int b = blockIdx.x;
    int t = threadIdx.x;
    const float* f = im_feat + b * 512;
    float s0 = 0.f, s1 = 0.f;
    for (int i = t; i < 512; i += 64) {
        float v = f[i];
        s0 = fmaf(v, pos_w[i], s0);        // row 0 -> mu
        s1 = fmaf(v, pos_w[512 + i], s1);  // row 1 -> rho
    }
    for (int off = 32; off > 0; off >>= 1) {
        s0 += __shfl_down(s0, off, 64);
        s1 += __shfl_down(s1, off, 64);
    }
    if (t == 0) {
        float mu  = s0 + pos_b[0];
        float rho = s1 + pos_b[1];
        float cm = cosf(mu),  sm = sinf(mu);
        float cr = cosf(rho), sr = sinf(rho);
        float* R = Rout + b * 16;
        R[0] = cm;   R[1] = sm * sr;  R[2] = -sm * cr;
        R[3] = 0.f;  R[4] = cr;       R[5] = sr;
        R[6] = sm;   R[7] = -cm * sr; R[8] = cm * cr;
    }
}

// Kernel 2: one thread per (b,d,h,w); trilinear sample of 4 channels.
__global__ __launch_bounds__(256) void sample_kernel(const float* __restrict__ x,
                                                     const float* __restrict__ Rin,
                                                     float* __restrict__ out) {
    unsigned tid = blockIdx.x * 256u + threadIdx.x;
    int w = tid & 127;
    int h = (tid >> 7) & 127;
    int d = (tid >> 14) & 127;
    int b = tid >> 21;

    const float* R = Rin + b * 16;
    const float step = 2.0f / 127.0f;
    float X = fmaf((float)w, step, -1.0f);
    float Y = fmaf((float)h, step, -1.0f);
    float Z = fmaf((float)d, step, -1.0f);

    // grid = R @ (X,Y,Z); R[3] == 0
    float gx = fmaf(R[0], X, fmaf(R[1], Y, R[2] * Z));
    float gy = fmaf(R[4], Y, R[5] * Z);
    float gz = fmaf(R[6], X, fmaf(R[7], Y, R[8] * Z));

    // unnormalize, align_corners=False: ix = ((g+1)*128 - 1)/2 = g*64 + 63.5
    float ix = fmaf(gx, 64.0f, 63.5f);
    float iy = fmaf(gy, 64.0f, 63.5f);
    float iz = fmaf(gz, 64.0f, 63.5f);

    float fx0 = floorf(ix), fy0 = floorf(iy), fz0 = floorf(iz);
    float fx = ix - fx0, fy = iy - fy0, fz = iz - fz0;
    int ix0 = (int)fx0, iy0 = (int)fy0, iz0 = (int)fz0;
    int ix1 = ix0 + 1, iy1 = iy0 + 1, iz1 = iz0 + 1;

    // validity folded into per-axis weights (zero padding)
    float wx0 = ((unsigned)ix0 < 128u) ? (1.f - fx) : 0.f;
    float wx1 = ((unsigned)ix1 < 128u) ? fx : 0.f;
    float wy0 = ((unsigned)iy0 < 128u) ? (1.f - fy) : 0.f;
    float wy1 = ((unsigned)iy1 < 128u) ? fy : 0.f;
    float wz0 = ((unsigned)iz0 < 128u) ? (1.f - fz) : 0.f;
    float wz1 = ((unsigned)iz1 < 128u) ? fz : 0.f;

    // clamped indices (loads always in-bounds; zero weight kills invalid)
    int xc0 = min(max(ix0, 0), 127), xc1 = min(max(ix1, 0), 127);
    int yc0 = min(max(iy0, 0), 127), yc1 = min(max(iy1, 0), 127);
    int zc0 = min(max(iz0, 0), 127), zc1 = min(max(iz1, 0), 127);

    int r00 = (zc0 * 128 + yc0) * 128;  // z0,y0
    int r01 = (zc0 * 128 + yc1) * 128;  // z0,y1
    int r10 = (zc1 * 128 + yc0) * 128;  // z1,y0
    int r11 = (zc1 * 128 + yc1) * 128;  // z1,y1

    float w00 = wz0 * wy0, w01 = wz0 * wy1, w10 = wz1 * wy0, w11 = wz1 * wy1;

    unsigned spatial = tid & (DHW - 1);
    const float* xb = x + (size_t)(b << 2) * DHW;
    float* ob = out + (size_t)(b << 2) * DHW + spatial;

#pragma unroll
    for (int c = 0; c < 4; ++c) {
        const float* xc = xb + (size_t)c * DHW;
        float v;
        v  = (xc[r00 + xc0] * wx0 + xc[r00 + xc1] * wx1) * w00;
        v += (xc[r01 + xc0] * wx0 + xc[r01 + xc1] * wx1) * w01;
        v += (xc[r10 + xc0] * wx0 + xc[r10 + xc1] * wx1) * w10;
        v += (xc[r11 + xc0] * wx0 + xc[r11 + xc1] * wx1) * w11;
        ob[(size_t)c * DHW] = v;
    }
}

extern "C" void kernel_launch(void* const* d_in, const int* in_sizes, int n_in,
                              void* d_out, int out_size, void* d_ws, size_t ws_size,
                              hipStream_t stream) {
    const float* x       = (const float*)d_in[0];
    const float* im_feat = (const float*)d_in[1];
    const float* pos_w   = (const float*)d_in[2];
    const float* pos_b   = (const float*)d_in[3];
    float* out = (float*)d_out;
    float* Rws = (float*)d_ws;

    compute_R_kernel<<<8, 64, 0, stream>>>(im_feat, pos_w, pos_b, Rws);
    int total = 8 * DHW;
    sample_kernel<<<total / 256, 256, 0, stream>>>(x, Rws, out);
}